// Round 10
// baseline (794.732 us; speedup 1.0000x reference)
//
#include <hip/hip_runtime.h>
#include <hip/hip_bf16.h>
#include <stdint.h>

#define KDIM 1024
#define NROW 4096
#define NCOL 4096
#define INFV 1e30f
#define INFBITS 0x7149F2CAu     // bits of 1e30f
#define BM 128
#define BK 32

#define SKROWS 4160             // skewed cost rows
#define EMAX   275              // 260 blocks + 5*3 stripe lag

typedef __bf16 bf16x8 __attribute__((ext_vector_type(8)));
typedef float f32x4 __attribute__((ext_vector_type(4)));

#define CFENCE asm volatile("" ::: "memory")

__device__ __forceinline__ unsigned short f2bf(float f) {
    __hip_bfloat16 h = __float2bfloat16(f);
    return *reinterpret_cast<unsigned short*>(&h);
}

__device__ __forceinline__ void gll16(const void* gsrc, void* ldst) {
    __builtin_amdgcn_global_load_lds(
        (const __attribute__((address_space(1))) void*)gsrc,
        (__attribute__((address_space(3))) void*)ldst, 16, 0, 0);
}

// ---------------------------------------------------------------------------
// Kernel 1: row-normalize both trajectories, emit bf16
// ---------------------------------------------------------------------------
__global__ __launch_bounds__(256) void normalize_bf16(
    const float* __restrict__ t1, const float* __restrict__ t2,
    unsigned short* __restrict__ o1, unsigned short* __restrict__ o2)
{
    int b = blockIdx.x;
    int t = threadIdx.x;
    const float* src;
    unsigned short* dst;
    if (b < NROW) { src = t1 + (size_t)b * KDIM;          dst = o1 + (size_t)b * KDIM; }
    else          { src = t2 + (size_t)(b - NROW) * KDIM; dst = o2 + (size_t)(b - NROW) * KDIM; }

    float4 v = reinterpret_cast<const float4*>(src)[t];
    float ss = v.x * v.x + v.y * v.y + v.z * v.z + v.w * v.w;
    #pragma unroll
    for (int d = 32; d >= 1; d >>= 1) ss += __shfl_xor(ss, d, 64);

    __shared__ float wsum[4];
    int wave = t >> 6;
    if ((t & 63) == 0) wsum[wave] = ss;
    __syncthreads();
    float inv = 1.0f / (sqrtf(wsum[0] + wsum[1] + wsum[2] + wsum[3]) + 1e-8f);

    ushort4 o;
    o.x = f2bf(v.x * inv);
    o.y = f2bf(v.y * inv);
    o.z = f2bf(v.z * inv);
    o.w = f2bf(v.w * inv);
    reinterpret_cast<ushort4*>(dst)[t] = o;
}

// ---------------------------------------------------------------------------
// Kernel 2: skewed cost: skew[i + ((j>>2)&63)][j] = 1 - dot(t1n[i], t2n[j])
// ---------------------------------------------------------------------------
__global__ __launch_bounds__(256) void gemm_cost(
    const unsigned short* __restrict__ A,
    const unsigned short* __restrict__ B,
    unsigned short* __restrict__ Cs)    // skewed [SKROWS][4096]
{
    __shared__ __align__(16) unsigned short As[BM * BK];
    __shared__ __align__(16) unsigned short Bs[BM * BK];

    int t    = threadIdx.x;
    int lane = t & 63;
    int wave = t >> 6;
    int i0   = blockIdx.y * BM;
    int j0   = blockIdx.x * BM;

    f32x4 acc[4][4];
    f32x4 zero = {0.f, 0.f, 0.f, 0.f};
    #pragma unroll
    for (int m = 0; m < 4; ++m)
        #pragma unroll
        for (int n = 0; n < 4; ++n) acc[m][n] = zero;

    int frow = lane & 15;
    int fk   = (lane >> 4) * 8;
    int wr   = (wave >> 1) * 64;
    int wc   = (wave & 1) * 64;

    int srow = t >> 2;
    int scb  = (t & 3) * 8;

    uint4 ra0, ra1, rb0, rb1;
    {
        ra0 = *reinterpret_cast<const uint4*>(A + (size_t)(i0 + srow) * KDIM + scb);
        ra1 = *reinterpret_cast<const uint4*>(A + (size_t)(i0 + 64 + srow) * KDIM + scb);
        rb0 = *reinterpret_cast<const uint4*>(B + (size_t)(j0 + srow) * KDIM + scb);
        rb1 = *reinterpret_cast<const uint4*>(B + (size_t)(j0 + 64 + srow) * KDIM + scb);
    }

    for (int k0 = 0; k0 < KDIM; k0 += BK) {
        __syncthreads();
        *reinterpret_cast<uint4*>(As + (size_t)t * 8)         = ra0;
        *reinterpret_cast<uint4*>(As + (size_t)(256 + t) * 8) = ra1;
        *reinterpret_cast<uint4*>(Bs + (size_t)t * 8)         = rb0;
        *reinterpret_cast<uint4*>(Bs + (size_t)(256 + t) * 8) = rb1;
        __syncthreads();

        if (k0 + BK < KDIM) {
            int kn = k0 + BK;
            ra0 = *reinterpret_cast<const uint4*>(A + (size_t)(i0 + srow) * KDIM + kn + scb);
            ra1 = *reinterpret_cast<const uint4*>(A + (size_t)(i0 + 64 + srow) * KDIM + kn + scb);
            rb0 = *reinterpret_cast<const uint4*>(B + (size_t)(j0 + srow) * KDIM + kn + scb);
            rb1 = *reinterpret_cast<const uint4*>(B + (size_t)(j0 + 64 + srow) * KDIM + kn + scb);
        }

        bf16x8 af[4], bfr[4];
        #pragma unroll
        for (int m = 0; m < 4; ++m)
            af[m] = *reinterpret_cast<const bf16x8*>(As + (wr + m * 16 + frow) * BK + fk);
        #pragma unroll
        for (int n = 0; n < 4; ++n)
            bfr[n] = *reinterpret_cast<const bf16x8*>(Bs + (wc + n * 16 + frow) * BK + fk);

        #pragma unroll
        for (int m = 0; m < 4; ++m)
            #pragma unroll
            for (int n = 0; n < 4; ++n)
                acc[m][n] = __builtin_amdgcn_mfma_f32_16x16x32_bf16(af[m], bfr[n], acc[m][n], 0, 0, 0);
    }

    int crow = (lane >> 4) * 4;
    int ccol = lane & 15;
    #pragma unroll
    for (int n = 0; n < 4; ++n) {
        const int j  = j0 + wc + n * 16 + ccol;
        const int Lj = (j >> 2) & 63;
        #pragma unroll
        for (int m = 0; m < 4; ++m) {
            const int ibase = i0 + wr + m * 16 + crow;
            #pragma unroll
            for (int q = 0; q < 4; ++q)
                Cs[(size_t)(ibase + q + Lj) * NCOL + j] = f2bf(1.0f - acc[m][n][q]);
        }
    }
}

// ---------------------------------------------------------------------------
// Kernel 3: systolic DTW, 4 WGs x 4 waves (one wave per SIMD).
// Stripe s = 4*w + v owns cols [256s, 256s+256); lane L: 4 cols; step t ->
// row t-L. Wave v processes block e-5v at barrier epoch e; intra-WG handoff
// through LDS outRow ring (lockstep via lgkmcnt(0)+s_barrier, no vmcnt
// drain). 3 WG interfaces on the global ring (producer atomic_exchange for
// coherent-point visibility; consumer tagged preloads + rare poll).
// Cost staging: 4-slot LDS ring per wave, prefetch 3 AHEAD (slot (ib+3)&3
// never equals read slot ib&3 -> no DMA-overwrite race; this was R8's bug).
// Exact VMEM counts per epoch -> s_waitcnt vmcnt(24/27/28).
// ---------------------------------------------------------------------------
__global__ __launch_bounds__(256, 1) void dtw_systolic(
    const unsigned short* __restrict__ cost,   // skewed [SKROWS][4096]
    unsigned long long* __restrict__ ring,     // [3][4096] + garb[4][64]
    float* __restrict__ out)
{
    __shared__ __align__(16) unsigned char clds[4 * 4 * 8192];  // [wave][slot][8KB]
    __shared__ float outRow[4][128];    // row-indexed boundary ring per stripe
    __shared__ float outRowD[4][128];   // dump for lanes != 63

    const int w    = blockIdx.x;
    const int tid  = threadIdx.x;
    const int v    = tid >> 6;
    const int lane = tid & 63;
    const int stripe = 4 * w + v;
    const bool gCon  = (v == 0 && w > 0);
    const bool gPro  = (v == 3 && w < 3);
    const bool first = (stripe == 0);
    const char* skewb = (const char*)cost;
    const unsigned long long* rseg = ring + (size_t)(w > 0 ? w - 1 : 0) * 4096;
    unsigned long long* wseg = ring + (size_t)w * 4096;
    unsigned long long* garb = ring + (size_t)3 * 4096 + w * 64;
    const unsigned lmin = (lane < 16) ? (unsigned)lane : 15u;
    const unsigned stripeByte = (unsigned)stripe * 512u + ((unsigned)(lane & 31) << 4);
    unsigned char* myclds = clds + v * 32768;
    float* opw = (lane == 63) ? outRow[v] : outRowD[v];

    float pd0 = INFV, pd1 = INFV, pd2 = INFV, pd3 = INFV;
    float lprev = (first && lane == 0) ? 0.0f : INFV;   // DP origin seed
    float d3p = INFV;
    unsigned ansb = INFBITS;
    unsigned long long rv0 = 0, rv1 = 0, rv2 = 0;

#define GLL8(STG) { int sg_ = (STG); sg_ = sg_ < 0 ? 0 : (sg_ > 259 ? 259 : sg_); \
    unsigned char* ldsb_ = myclds + (sg_ & 3) * 8192; \
    _Pragma("unroll") \
    for (int g_ = 0; g_ < 8; ++g_) { \
        int sr_ = 16 * sg_ + 2 * g_ + (lane >> 5); \
        if (sr_ > SKROWS - 1) sr_ = SKROWS - 1; \
        gll16(skewb + (size_t)sr_ * 8192 + stripeByte, ldsb_ + g_ * 1024); } }

#define RINGLD(DST, BI) { int pb_ = (BI); pb_ = pb_ < 0 ? 0 : (pb_ > 255 ? 255 : pb_); \
    DST = __hip_atomic_load(rseg + 16u * (unsigned)pb_ + lmin, \
                            __ATOMIC_RELAXED, __HIP_MEMORY_SCOPE_AGENT); }

#define DSTEP(K) { \
    const uint2 cu = *reinterpret_cast<const uint2*>(ldsaddr + (K) * 512); \
    const unsigned rbK = (unsigned)__builtin_amdgcn_readlane(rvhi, (K)); \
    const float lcur = __uint_as_float((unsigned)__builtin_amdgcn_update_dpp( \
        (int)rbK, (int)__float_as_uint(d3p), 0x138, 0xf, 0xf, false)); \
    const float c0 = __uint_as_float(cu.x << 16); \
    const float c1 = __uint_as_float(cu.x & 0xffff0000u); \
    const float c2 = __uint_as_float(cu.y << 16); \
    const float c3 = __uint_as_float(cu.y & 0xffff0000u); \
    const float n0 = c0 + fminf(pd0, lprev); \
    const float n1 = c1 + fminf(pd1, pd0); \
    const float n2 = c2 + fminf(pd2, pd1); \
    const float n3 = c3 + fminf(pd3, pd2); \
    const float e0 = fminf(lcur + c0, n0); \
    const float e1 = fminf(e0 + c1, n1); \
    const float e2 = fminf(e1 + c2, n2); \
    const float e3 = fminf(e2 + c3, n3); \
    opw[(unsigned)(rowbase + (K)) & 127u] = e3; \
    ansb = (tjb + (K) == 4158) ? __float_as_uint(e3) : ansb; \
    lprev = lcur; d3p = e3; \
    pd0 = e0; pd1 = e1; pd2 = e2; pd3 = e3; }

    // prologue: only v==0 lacks idle epochs -> stage blocks 0..2 (+ring preload)
    if (v == 0) {
        if (gCon) { GLL8(0) RINGLD(rv0, 0) GLL8(1) RINGLD(rv1, 1)
                    GLL8(2) RINGLD(rv2, 2) }
        else      { GLL8(0) GLL8(1) GLL8(2) }
    }

    #pragma unroll 1
    for (int e = 0; e < EMAX; ++e) {
        CFENCE;
        asm volatile("s_waitcnt lgkmcnt(0)" ::: "memory");  // LDS writes visible
        __builtin_amdgcn_s_barrier();
        CFENCE;

        const int ib = e - 5 * v;          // this wave's block this epoch

        GLL8(ib + 3)                       // prefetch 3 ahead: slot != read slot
        unsigned long long rvN = 0;
        if (gCon) RINGLD(rvN, ib + 3)

        if (gCon)      { asm volatile("s_waitcnt vmcnt(28)" ::: "memory"); }
        else if (gPro) { asm volatile("s_waitcnt vmcnt(27)" ::: "memory"); }
        else           { asm volatile("s_waitcnt vmcnt(24)" ::: "memory"); }

        if (ib >= 0 && ib < 260) {
            // resolve boundary input (lanes 0..15 hold rows 16ib..16ib+15)
            int rvhi;
            if (gCon) {
                if (ib < 256) {
                    const unsigned expt = 16u * (unsigned)ib + lmin + 1u;
                    while (__ballot((unsigned)rv0 == expt) != ~0ull)
                        rv0 = __hip_atomic_load(rseg + 16u * (unsigned)ib + lmin,
                                                __ATOMIC_RELAXED, __HIP_MEMORY_SCOPE_AGENT);
                }
                rvhi = (int)(unsigned)(rv0 >> 32);
            } else if (v > 0) {
                rvhi = (int)__float_as_uint(
                    outRow[v - 1][(16u * (unsigned)ib + lmin) & 127u]);
            } else {
                rvhi = (int)INFBITS;        // stripe 0: left edge = +INF
            }

            const unsigned char* ldsaddr = myclds + (ib & 3) * 8192 + (lane << 3);
            const int rowbase = 16 * ib - 63;
            const int tjb = 16 * ib;

            DSTEP(0)  DSTEP(1)  DSTEP(2)  DSTEP(3)
            DSTEP(4)  DSTEP(5)  DSTEP(6)  DSTEP(7)
            DSTEP(8)  DSTEP(9)  DSTEP(10) DSTEP(11)
            DSTEP(12) DSTEP(13) DSTEP(14) DSTEP(15)
        }

        if (gPro) {     // publish this block's 16 boundary rows (or garb)
            const int r = 16 * ib - 63 + (int)lmin;
            const float bv = outRow[3][(unsigned)r & 127u];
            const bool valid = (lane < 16) && (ib >= 0) && (ib < 260) &&
                               (r >= 0) && (r <= 4095);
            if (lane < 16) {
                const unsigned long long pk =
                    ((unsigned long long)__float_as_uint(bv) << 32) | (unsigned)(r + 1);
                unsigned long long* sp = valid ? (wseg + r) : (garb + lane);
                (void)__hip_atomic_exchange(sp, pk, __ATOMIC_RELAXED,
                                            __HIP_MEMORY_SCOPE_AGENT);
            }
        }

        rv0 = rv1; rv1 = rv2; rv2 = rvN;
    }

#undef GLL8
#undef RINGLD
#undef DSTEP

    if (stripe == 15 && lane == 63) out[0] = 1.0f / (1.0f + __uint_as_float(ansb));
}

// ---------------------------------------------------------------------------
extern "C" void kernel_launch(void* const* d_in, const int* in_sizes, int n_in,
                              void* d_out, int out_size, void* d_ws, size_t ws_size,
                              hipStream_t stream)
{
    const float* t1 = (const float*)d_in[0];
    const float* t2 = (const float*)d_in[1];
    float* out = (float*)d_out;

    char* ws = (char*)d_ws;
    unsigned short* t1n  = (unsigned short*)ws;                                   // 8 MB
    unsigned short* t2n  = (unsigned short*)(ws + (size_t)NROW * KDIM * 2);       // 8 MB
    unsigned short* skew = (unsigned short*)(ws + (size_t)16 * 1024 * 1024);      // 34.1 MB
    unsigned long long* ring = (unsigned long long*)(ws + (size_t)52 * 1024 * 1024);
    // ring: 3 interface segments x 4096 slots + 4x64 garb slots (~130 KB)

    hipMemsetAsync(ring, 0, (size_t)(3 * 4096 + 4 * 64) * 8, stream);
    normalize_bf16<<<2 * NROW, 256, 0, stream>>>(t1, t2, t1n, t2n);
    gemm_cost<<<dim3(NCOL / BM, NROW / BM), 256, 0, stream>>>(t1n, t2n, skew);
    dtw_systolic<<<4, 256, 0, stream>>>(skew, ring, out);
}